// Round 4
// baseline (218.963 us; speedup 1.0000x reference)
//
#include <hip/hip_runtime.h>
#include <hip/hip_bf16.h>

#define DEVFN __device__ __forceinline__

typedef __bf16 bf16x8 __attribute__((ext_vector_type(8)));
typedef float f32x4 __attribute__((ext_vector_type(4)));
typedef unsigned short ushort8 __attribute__((ext_vector_type(8)));
typedef unsigned short us4 __attribute__((ext_vector_type(4)));

namespace {

constexpr int S = 1024;
constexpr int HID = 768;
constexpr int NH = 12;
constexpr int HD = 64;

DEVFN unsigned short f2bf(float f) {
  union { float f; unsigned u; } v; v.f = f;
  unsigned r = v.u + 0x7FFF + ((v.u >> 16) & 1);   // RNE
  return (unsigned short)(r >> 16);
}

DEVFN float bf2f(unsigned short u) {
  union { unsigned u; float f; } v; v.u = ((unsigned)u) << 16; return v.f;
}

DEVFN f32x4 zero4() { return f32x4{0.f, 0.f, 0.f, 0.f}; }

DEVFN f32x4 mfma_bf16(bf16x8 a, bf16x8 b, f32x4 c) {
  return __builtin_amdgcn_mfma_f32_16x16x32_bf16(a, b, c, 0, 0, 0);
}

// async global->LDS, 16B per lane; dest = lds_base + lane*16 (wave-uniform base)
DEVFN void gload16(void* lds_base, const void* gsrc) {
  __builtin_amdgcn_global_load_lds(
      (const __attribute__((address_space(1))) void*)gsrc,
      (__attribute__((address_space(3))) void*)lds_base, 16, 0, 0);
}

// read one MFMA fragment (8 contiguous bf16) from a [rows][64] bf16 LDS tile
// stored with chunk-XOR swizzle: LDS[row][ch] = G[row][ch ^ (row&7)]
DEVFN bf16x8 frag_ld(const char* tile, int row, int ch) {
  int chs = ch ^ (row & 7);
  return *(const bf16x8*)(tile + row * 128 + chs * 16);
}

// ---------------------------------------------------------------- K0: preps
__global__ void k0_cvt_x(const float* __restrict__ x, unsigned short* __restrict__ xb) {
  size_t i = (size_t)(blockIdx.x * 256 + threadIdx.x) * 8;
  float4 a = *(const float4*)(x + i);
  float4 c = *(const float4*)(x + i + 4);
  ushort8 o;
  o[0] = f2bf(a.x); o[1] = f2bf(a.y); o[2] = f2bf(a.z); o[3] = f2bf(a.w);
  o[4] = f2bf(c.x); o[5] = f2bf(c.y); o[6] = f2bf(c.z); o[7] = f2bf(c.w);
  *(ushort8*)(xb + i) = o;
}

// dist_emb [2047][64] f32 -> [2048][64] bf16 (row 2047 zero-padded)
__global__ void k0_cvt_pe(const float* __restrict__ de, unsigned short* __restrict__ peb) {
  size_t i = (size_t)(blockIdx.x * 256 + threadIdx.x) * 8;
  int row = (int)(i >> 6);
  ushort8 o;
  if (row < 2047) {
    float4 a = *(const float4*)(de + i);
    float4 c = *(const float4*)(de + i + 4);
    o[0] = f2bf(a.x); o[1] = f2bf(a.y); o[2] = f2bf(a.z); o[3] = f2bf(a.w);
    o[4] = f2bf(c.x); o[5] = f2bf(c.y); o[6] = f2bf(c.z); o[7] = f2bf(c.w);
  } else {
    o = ushort8{0, 0, 0, 0, 0, 0, 0, 0};
  }
  *(ushort8*)(peb + i) = o;
}

// W[k][n] f32 -> wt[sec*768+n][k] bf16  (64x64 LDS tile transpose)
__global__ __launch_bounds__(256) void k0_wt(const float* __restrict__ Wq,
                                             const float* __restrict__ Wk,
                                             const float* __restrict__ Wv,
                                             unsigned short* __restrict__ wt) {
  __shared__ float t[64][65];
  int bidx = blockIdx.x;                 // 3 * 12 * 12 = 432
  int sec = bidx / 144, rem = bidx % 144;
  int ktb = rem / 12, ntb = rem % 12;
  const float* W = (sec == 0) ? Wq : ((sec == 1) ? Wk : Wv);
  int k0 = ktb * 64, n0 = ntb * 64;
  int tid = threadIdx.x;
  #pragma unroll
  for (int p = 0; p < 4; ++p) {
    int id = p * 256 + tid;              // 0..1023
    int row = id >> 4, ch = id & 15;
    float4 v = *(const float4*)(W + (size_t)(k0 + row) * 768 + n0 + ch * 4);
    t[row][ch * 4 + 0] = v.x; t[row][ch * 4 + 1] = v.y;
    t[row][ch * 4 + 2] = v.z; t[row][ch * 4 + 3] = v.w;
  }
  __syncthreads();
  #pragma unroll
  for (int p = 0; p < 2; ++p) {
    int id = p * 256 + tid;              // 0..511
    int nrow = id >> 3, c8 = id & 7;
    ushort8 o;
    #pragma unroll
    for (int i = 0; i < 8; ++i) o[i] = f2bf(t[c8 * 8 + i][nrow]);
    *(ushort8*)(wt + (size_t)(sec * 768 + n0 + nrow) * 768 + k0 + c8 * 8) = o;
  }
}

// ------------------------------------------------- K1: fused QKV projection
__global__ __launch_bounds__(256) void k1_qkv(
    const unsigned short* __restrict__ xb, const unsigned short* __restrict__ wt,
    const float* __restrict__ bq, const float* __restrict__ bk, const float* __restrict__ bv,
    unsigned short* __restrict__ q_ws, unsigned short* __restrict__ k_ws,
    unsigned short* __restrict__ vt_ws) {
  __shared__ char ldsA[8192], ldsB[8192];
  const int tid = threadIdx.x, lane = tid & 63, wv = tid >> 6;
  const int row16 = lane & 15, cgrp = lane >> 4;
  const int ntb = blockIdx.x % 36, mtb = blockIdx.x / 36;
  const int sec = ntb / 12;
  const int n0 = ntb * 64;
  const int m0 = mtb * 64;

  f32x4 acc[4] = {zero4(), zero4(), zero4(), zero4()};

  for (int k0 = 0; k0 < 768; k0 += 64) {
    #pragma unroll
    for (int c = 0; c < 2; ++c) {
      int cc = (wv * 2 + c) * 64 + lane;
      int row = cc >> 3, ch = cc & 7, chs = ch ^ (row & 7);
      gload16(ldsA + (wv * 2 + c) * 1024, xb + (size_t)(m0 + row) * 768 + k0 + chs * 8);
      gload16(ldsB + (wv * 2 + c) * 1024, wt + (size_t)(n0 + row) * 768 + k0 + chs * 8);
    }
    __syncthreads();
    if (sec < 2) {
      bf16x8 af[2];
      #pragma unroll
      for (int k2 = 0; k2 < 2; ++k2) af[k2] = frag_ld(ldsA, wv * 16 + row16, k2 * 4 + cgrp);
      #pragma unroll
      for (int nt = 0; nt < 4; ++nt)
        #pragma unroll
        for (int k2 = 0; k2 < 2; ++k2) {
          bf16x8 bf = frag_ld(ldsB, nt * 16 + row16, k2 * 4 + cgrp);
          acc[nt] = mfma_bf16(af[k2], bf, acc[nt]);
        }
    } else {
      bf16x8 af[2];
      #pragma unroll
      for (int k2 = 0; k2 < 2; ++k2) af[k2] = frag_ld(ldsB, wv * 16 + row16, k2 * 4 + cgrp);
      #pragma unroll
      for (int mt = 0; mt < 4; ++mt)
        #pragma unroll
        for (int k2 = 0; k2 < 2; ++k2) {
          bf16x8 bx = frag_ld(ldsA, mt * 16 + row16, k2 * 4 + cgrp);
          acc[mt] = mfma_bf16(af[k2], bx, acc[mt]);
        }
    }
    __syncthreads();
  }

  if (sec < 2) {
    unsigned short* dst = (sec == 0) ? q_ws : k_ws;
    const float* bias = (sec == 0) ? bq : bk;
    int nl0 = (ntb % 12) * 64;
    #pragma unroll
    for (int nt = 0; nt < 4; ++nt) {
      int nn = nl0 + nt * 16 + row16;
      float bb = bias[nn];
      int hh = nn >> 6, dd = nn & 63;
      #pragma unroll
      for (int j = 0; j < 4; ++j) {
        int m = m0 + wv * 16 + cgrp * 4 + j;
        int b_ = m >> 10, s_ = m & 1023;
        dst[(size_t)((b_ * 12 + hh) * 1024 + s_) * 64 + dd] = f2bf(acc[nt][j] + bb);
      }
    }
  } else {
    int nl0 = (ntb % 12) * 64;
    #pragma unroll
    for (int j = 0; j < 4; ++j) {
      int nn = nl0 + wv * 16 + cgrp * 4 + j;
      float bb = bv[nn];
      int hh = nn >> 6, dd = nn & 63;
      #pragma unroll
      for (int mt = 0; mt < 4; ++mt) {
        int m = m0 + mt * 16 + row16;
        int b_ = m >> 10, s_ = m & 1023;
        vt_ws[(size_t)((b_ * 12 + hh) * 64 + dd) * 1024 + s_] = f2bf(acc[mt][j] + bb);
      }
    }
  }
}

// ---------------- KA: fully fused attention per (bh, 32-row Q-tile)
// grid: 48 bh * 32 qt = 1536 blocks; 4 waves, each a 16(l)x32(r) quadrant
// (wl = row half, wr = col half). p stripe kept in LDS; no HBM round-trip.
// rt loop is barrier-free: s3 scratch is wave-private, p_lds bytes are
// wave-disjoint. One barrier, then PV MFMA + streaming normalized probs.
__global__ __launch_bounds__(256) void kA_attn(
    const unsigned short* __restrict__ q_ws, const unsigned short* __restrict__ k_ws,
    const unsigned short* __restrict__ vt_ws, const unsigned short* __restrict__ peb,
    const float* __restrict__ mask, float* __restrict__ out_ctx,
    float* __restrict__ out_probs) {
  __shared__ unsigned short p_lds[32 * 1024];     // [row][col] chunk-swizzled, 64KB
  __shared__ unsigned short s3t[4][48 * 36];      // per-wave [jj][dr], bf16
  __shared__ float rsp[32][2];

  const int tid = threadIdx.x, lane = tid & 63, wv = tid >> 6;
  const int wl = wv >> 1, wr = wv & 1;
  const int row16 = lane & 15, cgrp = lane >> 4;

  const int qt = blockIdx.x & 31, bh = blockIdx.x >> 5;
  const int b = bh / NH, h = bh % NH;
  const int l0 = qt * 32;

  const unsigned short* qh = q_ws + (size_t)bh * S * HD;
  const unsigned short* khp = k_ws + (size_t)bh * S * HD;
  const unsigned short* vth = vt_ws + (size_t)bh * HD * S;
  const float* maskb = mask + b * S;

  // persistent Q fragments: rows l0 + wl*16 + row16
  bf16x8 qf[2];
  #pragma unroll
  for (int k2 = 0; k2 < 2; ++k2)
    qf[k2] = *(const bf16x8*)(qh + (size_t)(l0 + wl * 16 + row16) * HD + k2 * 32 + cgrp * 8);

  unsigned short* s3w = &s3t[wv][0];
  float rs[4] = {0.f, 0.f, 0.f, 0.f};

  for (int rt = 0; rt < 16; ++rt) {
    const int rbase = rt * 64 + wr * 32;

    // K fragments (L2-resident; per-lane 16B at 128B row stride)
    bf16x8 kf[2][2];
    #pragma unroll
    for (int rtl = 0; rtl < 2; ++rtl)
      #pragma unroll
      for (int k2 = 0; k2 < 2; ++k2)
        kf[rtl][k2] = *(const bf16x8*)(khp + (size_t)(rbase + rtl * 16 + row16) * HD +
                                       k2 * 32 + cgrp * 8);

    // PE fragments: jj = dl - dr + 31 in [0,47); pe row = pe_base + jj
    const int pe_base = l0 + wl * 16 - rbase + 992;   // in [0, 2000]
    bf16x8 pef[3][2];
    #pragma unroll
    for (int jt = 0; jt < 3; ++jt)
      #pragma unroll
      for (int k2 = 0; k2 < 2; ++k2)
        pef[jt][k2] = *(const bf16x8*)(peb + (size_t)(pe_base + jt * 16 + row16) * HD +
                                       k2 * 32 + cgrp * 8);

    // S3 = K @ PE^T -> wave-private LDS [jj][dr] (col=lane&15 is PE row = jj)
    #pragma unroll
    for (int rtl = 0; rtl < 2; ++rtl)
      #pragma unroll
      for (int jt = 0; jt < 3; ++jt) {
        f32x4 a3 = zero4();
        a3 = mfma_bf16(kf[rtl][0], pef[jt][0], a3);
        a3 = mfma_bf16(kf[rtl][1], pef[jt][1], a3);
        us4 o;
        o[0] = f2bf(a3[0]); o[1] = f2bf(a3[1]); o[2] = f2bf(a3[2]); o[3] = f2bf(a3[3]);
        *(us4*)(s3w + (jt * 16 + row16) * 36 + rtl * 16 + cgrp * 4) = o;
      }

    // S1 = Q @ K^T
    f32x4 s1[2];
    #pragma unroll
    for (int rtl = 0; rtl < 2; ++rtl) {
      f32x4 a = zero4();
      a = mfma_bf16(qf[0], kf[rtl][0], a);
      a = mfma_bf16(qf[1], kf[rtl][1], a);
      s1[rtl] = a;
    }
    // S2 = Q @ PE^T (registers; col=lane&15 is jj within tile)
    f32x4 s2[3];
    #pragma unroll
    for (int jt = 0; jt < 3; ++jt) {
      f32x4 a = zero4();
      a = mfma_bf16(qf[0], pef[jt][0], a);
      a = mfma_bf16(qf[1], pef[jt][1], a);
      s2[jt] = a;
    }

    // combine: diagonal gathers + exp -> p_lds (+ rowsum partials)
    #pragma unroll
    for (int rtl = 0; rtl < 2; ++rtl) {
      float mval = maskb[rbase + rtl * 16 + row16];
      const int jtA = 1 - rtl;
      #pragma unroll
      for (int j = 0; j < 4; ++j) {
        int dl = cgrp * 4 + j;
        int dr = rtl * 16 + row16;
        int jjq = dl - dr + 31;                     // [0,46]
        int src = (lane & 48) | (jjq & 15);
        float vA = __shfl(s2[jtA][j], src, 64);
        float vB = __shfl(s2[jtA + 1][j], src, 64);
        float b1 = ((jjq >> 4) == jtA) ? vA : vB;
        float b2 = bf2f(s3w[jjq * 36 + dr]);
        float logit = (s1[rtl][j] + b1 + b2) * 0.125f + mval;
        float p = __expf(logit);
        rs[j] += p;
        int prow = wl * 16 + dl;
        int pcol = rbase + dr;
        int chs = (pcol >> 3) ^ (prow & 7);        // XOR low 3 bits of chunk
        p_lds[prow * 1024 + chs * 8 + (pcol & 7)] = f2bf(p);
      }
    }
  }

  // rowsum partials: reduce over the 16 dr lanes -> rsp[row][wr]
  #pragma unroll
  for (int j = 0; j < 4; ++j) {
    float v = rs[j];
    v += __shfl_xor(v, 1, 64);
    v += __shfl_xor(v, 2, 64);
    v += __shfl_xor(v, 4, 64);
    v += __shfl_xor(v, 8, 64);
    if (row16 == 0) rsp[wl * 16 + cgrp * 4 + j][wr] = v;
  }
  __syncthreads();

  // ---- PV: ctx[16 rows][32 cols] per wave from LDS p (unnormalized) ----
  f32x4 ctxacc[2] = {zero4(), zero4()};
  {
    const int prow = wl * 16 + row16;
    for (int ks = 0; ks < 32; ++ks) {
      int chs = (ks * 4 + cgrp) ^ (prow & 7);
      bf16x8 pa = *(const bf16x8*)(p_lds + prow * 1024 + chs * 8);
      #pragma unroll
      for (int dt = 0; dt < 2; ++dt) {
        bf16x8 vb = *(const bf16x8*)(vth + (size_t)(wr * 32 + dt * 16 + row16) * S +
                                     ks * 32 + cgrp * 8);
        ctxacc[dt] = mfma_bf16(pa, vb, ctxacc[dt]);
      }
    }
  }
  #pragma unroll
  for (int dt = 0; dt < 2; ++dt)
    #pragma unroll
    for (int j = 0; j < 4; ++j) {
      int lr = wl * 16 + cgrp * 4 + j;
      float iv = 1.0f / (rsp[lr][0] + rsp[lr][1]);
      out_ctx[((size_t)(b * S + l0 + lr)) * HID + h * HD + wr * 32 + dt * 16 + row16] =
          ctxacc[dt][j] * iv;
    }

  // ---- streaming normalized probs write (read swizzled LDS, write linear) ----
  {
    const int wrow0 = tid >> 5;        // 0..7
    const int c32 = tid & 31;
    float* probs_bh = out_probs + (size_t)bh * S * S;
    #pragma unroll
    for (int rp = 0; rp < 4; ++rp) {
      int row = rp * 8 + wrow0;
      float iv = 1.0f / (rsp[row][0] + rsp[row][1]);
      float* dst = probs_bh + (size_t)(l0 + row) * S;
      #pragma unroll
      for (int cc = 0; cc < 4; ++cc) {
        int ch = cc * 32 + c32;
        int chs = ch ^ (row & 7);
        ushort8 w = *(const ushort8*)(p_lds + row * 1024 + chs * 8);
        float4 lo{bf2f(w[0]) * iv, bf2f(w[1]) * iv, bf2f(w[2]) * iv, bf2f(w[3]) * iv};
        float4 hi{bf2f(w[4]) * iv, bf2f(w[5]) * iv, bf2f(w[6]) * iv, bf2f(w[7]) * iv};
        *(float4*)(dst + ch * 8) = lo;
        *(float4*)(dst + ch * 8 + 4) = hi;
      }
    }
  }
}

}  // namespace

extern "C" void kernel_launch(void* const* d_in, const int* in_sizes, int n_in,
                              void* d_out, int out_size, void* d_ws, size_t ws_size,
                              hipStream_t stream) {
  const float* hidden = (const float*)d_in[0];
  const float* mask   = (const float*)d_in[1];
  const float* Wq = (const float*)d_in[2];
  const float* bq = (const float*)d_in[3];
  const float* Wk = (const float*)d_in[4];
  const float* bk = (const float*)d_in[5];
  const float* Wv = (const float*)d_in[6];
  const float* bv = (const float*)d_in[7];
  const float* de = (const float*)d_in[8];

  unsigned short* ws = (unsigned short*)d_ws;
  unsigned short* q_ws  = ws;               // 48*1024*64
  unsigned short* k_ws  = ws + 3145728;
  unsigned short* vt_ws = ws + 6291456;     // [bh][d][s]
  unsigned short* xb    = ws + 9437184;     // [4096][768]
  unsigned short* wt    = ws + 12582912;    // [2304][768]
  unsigned short* peb   = ws + 14352384;    // [2048][64]

  float* outc = (float*)d_out;
  float* outp = outc + (size_t)4 * 1024 * 768;

  hipLaunchKernelGGL(k0_cvt_x, dim3(1536), dim3(256), 0, stream, hidden, xb);
  hipLaunchKernelGGL(k0_cvt_pe, dim3(64), dim3(256), 0, stream, de, peb);
  hipLaunchKernelGGL(k0_wt, dim3(432), dim3(256), 0, stream, Wq, Wk, Wv, wt);
  hipLaunchKernelGGL(k1_qkv, dim3(2304), dim3(256), 0, stream,
                     xb, wt, bq, bk, bv, q_ws, k_ws, vt_ws);
  hipLaunchKernelGGL(kA_attn, dim3(1536), dim3(256), 0, stream,
                     q_ws, k_ws, vt_ws, peb, mask, outc, outp);
}